// Round 11
// baseline (157.904 us; speedup 1.0000x reference)
//
#include <hip/hip_runtime.h>
#include <math.h>

#define B_   4
#define C_   256
#define CQK  32
#define N_   4096
#define TM   64           // kv per chunk
#define PSS  72           // ps row stride (shorts)
#define VSH  (C_ * TM)    // one vs buffer: 16384 shorts (32 KB)
#define XT2  264          // proj xT row stride (shorts): 256 + 8 pad
#define VOS  40           // proj vout row stride (shorts): 32 + 8 pad

// 2-way fallback params
#define TQ2  64
#define HIT2W ((N_ / 2) / TM)    // 32
// 4-way params
#define TQ4  128
#define HIT4W ((N_ / 4) / TM)    // 16

typedef __attribute__((ext_vector_type(8))) short short8;
typedef __attribute__((ext_vector_type(4))) short short4v;
typedef __attribute__((ext_vector_type(4))) float f32x4;
typedef __attribute__((ext_vector_type(2))) unsigned int uint2v;

#if __has_builtin(__builtin_amdgcn_exp2f)
#define EXP2F(x) __builtin_amdgcn_exp2f(x)
#else
#define EXP2F(x) exp2f(x)
#endif

// global -> LDS direct DMA, 16B per lane; LDS dest is wave-uniform base + lane*16
typedef const __attribute__((address_space(1))) unsigned int* gas1_t;
typedef __attribute__((address_space(3))) unsigned int* las3_t;
__device__ __forceinline__ void gload_lds16(const unsigned short* g, unsigned short* l) {
    __builtin_amdgcn_global_load_lds((gas1_t)g, (las3_t)l, 16, 0, 0);
}

__device__ __forceinline__ unsigned short f2bf(float f) {
    unsigned u = __builtin_bit_cast(unsigned, f);
    u += 0x7fffu + ((u >> 16) & 1u);
    return (unsigned short)(u >> 16);
}
__device__ __forceinline__ float bf2f(unsigned short s) {
    return __builtin_bit_cast(float, (unsigned)s << 16);
}
__device__ __forceinline__ unsigned pack2bf(float a, float b) {
    unsigned ua = __builtin_bit_cast(unsigned, a) + 0x8000u;
    unsigned ub = __builtin_bit_cast(unsigned, b) + 0x8000u;
#if __has_builtin(__builtin_amdgcn_perm)
    return __builtin_amdgcn_perm(ub, ua, 0x07060302u);
#else
    return (ua >> 16) | (ub & 0xffff0000u);
#endif
}

// ---------- weights -> bf16 [320][256] + fp32 bias[320]; log2e folded into q ----------
__global__ __launch_bounds__(256) void cvt_w(
    const float* __restrict__ Wq, const float* __restrict__ bq,
    const float* __restrict__ Wk, const float* __restrict__ bk,
    const float* __restrict__ Wv, const float* __restrict__ bv,
    unsigned short* __restrict__ wbf, float* __restrict__ biasf)
{
    const float LOG2E = 1.4426950408889634f;
    const int r = blockIdx.x;   // 0..319
    const int t = threadIdx.x;
    const float* src = (r < 32) ? (Wq + r * C_)
                     : (r < 64) ? (Wk + (r - 32) * C_)
                                : (Wv + (r - 64) * C_);
    const float scale = (r < 32) ? LOG2E : 1.0f;
    wbf[r * C_ + t] = f2bf(src[t] * scale);
    if (t == 0)
        biasf[r] = (r < 32) ? bq[r] * LOG2E : (r < 64) ? bk[r - 32] : bv[r - 64];
}

// ---------- fused qkv projection v2: 512 blocks (2/CU), vectorized staging + stores ----------
__global__ __launch_bounds__(256, 2) void proj_qkv(
    const float* __restrict__ x, const unsigned short* __restrict__ wbf,
    const float* __restrict__ biasf,
    unsigned short* __restrict__ qb, unsigned short* __restrict__ kb,
    unsigned short* __restrict__ vb)
{
    __shared__ __align__(16) unsigned short xT[32 * XT2];
    __shared__ __align__(16) unsigned short vout[256 * VOS];
    __shared__ __align__(16) unsigned short qks[32 * 72];

    const int t    = threadIdx.x;
    const int w    = t >> 6;
    const int lane = t & 63;
    const int quad = lane >> 4;
    const int c16  = lane & 15;
    const int n0   = blockIdx.x * 32;
    const int b    = blockIdx.y;

    {
        const int c0 = (t >> 3) * 8;
        const int nq = t & 7;
        f32x4 xv[8];
#pragma unroll
        for (int i = 0; i < 8; ++i)
            xv[i] = *(const f32x4*)&x[((size_t)(b * C_) + c0 + i) * N_ + n0 + 4 * nq];
#pragma unroll
        for (int j = 0; j < 4; ++j) {
            short8 pk;
#pragma unroll
            for (int i = 0; i < 8; ++i) pk[i] = (short)f2bf(xv[i][j]);
            *(short8*)&xT[(4 * nq + j) * XT2 + c0] = pk;
        }
    }
    __syncthreads();

    f32x4 acc[5][2];
#pragma unroll
    for (int i = 0; i < 5; ++i)
#pragma unroll
        for (int nt = 0; nt < 2; ++nt) acc[i][nt] = (f32x4){0.f, 0.f, 0.f, 0.f};

    const unsigned short* wr = wbf + (size_t)(80 * w + c16) * C_ + quad * 8;

#pragma unroll
    for (int ks = 0; ks < 8; ++ks) {
        short8 af[5], bf[2];
#pragma unroll
        for (int i = 0; i < 5; ++i)
            af[i] = *(const short8*)(wr + (size_t)(16 * i) * C_ + 32 * ks);
#pragma unroll
        for (int nt = 0; nt < 2; ++nt)
            bf[nt] = *(const short8*)&xT[(16 * nt + c16) * XT2 + ks * 32 + quad * 8];
#pragma unroll
        for (int i = 0; i < 5; ++i)
#pragma unroll
            for (int nt = 0; nt < 2; ++nt)
                acc[i][nt] = __builtin_amdgcn_mfma_f32_16x16x32_bf16(af[i], bf[nt], acc[i][nt], 0, 0, 0);
    }

#pragma unroll
    for (int i = 0; i < 5; ++i) {
        const int OT = 5 * w + i;
        const int obase = OT * 16 + 4 * quad;
        const f32x4 bv4 = *(const f32x4*)&biasf[obase];
#pragma unroll
        for (int nt = 0; nt < 2; ++nt) {
            const int n = 16 * nt + c16;
            float vals[4];
#pragma unroll
            for (int r = 0; r < 4; ++r) vals[r] = acc[i][nt][r] + bv4[r];
            if (OT >= 4) {
#pragma unroll
                for (int r = 0; r < 4; ++r)
                    vout[(obase + r - 64) * VOS + n] = f2bf(vals[r]);
            } else {
                const int col = (OT < 2 ? 0 : 32) + (OT & 1) * 16 + 4 * quad;
                short4v pk;
#pragma unroll
                for (int r = 0; r < 4; ++r) pk[r] = (short)f2bf(vals[r]);
                *(short4v*)&qks[n * 72 + col] = pk;
            }
        }
    }
    __syncthreads();

#pragma unroll
    for (int p = 0; p < 4; ++p) {
        const int c   = 64 * p + (t >> 2);
        const int seg = t & 3;
        const short8 vv = *(const short8*)&vout[c * VOS + seg * 8];
        *(short8*)(vb + ((size_t)(b * C_) + c) * N_ + n0 + seg * 8) = vv;
    }
    if (w < 2) {
        unsigned short* dst = w ? kb : qb;
        const int coff = w ? 32 : 0;
#pragma unroll
        for (int h = 0; h < 2; ++h) {
            const int n = 16 * h + (lane >> 2);
            const int c = (lane & 3) * 8;
            const short8 v = *(const short8*)&qks[n * 72 + coff + c];
            *(short8*)(dst + ((size_t)(b * N_) + n0 + n) * 32 + c) = v;
        }
    }
}

// ---------- attn 4-way: TQ=128, TM=64, split-kv 4-way, single-buf DMA V, K in regs ----------
// grid 512: quarter = flat&3, b = (flat>>2)&3, q0 = (flat>>4)*128
// per iter: [DMA V(it) | S(it) on akpre | akpre=K(it+1)] sync [PV(it)] sync
__global__ __launch_bounds__(512, 4) void attn4_kernel(
    const unsigned short* __restrict__ qg,
    const unsigned short* __restrict__ kg,
    const unsigned short* __restrict__ vg,
    float* __restrict__ outp,          // [B][C][N] fp32 partial (quarter 0)
    unsigned short* __restrict__ Op1,  // quarters 1..3 bf16 partials
    unsigned short* __restrict__ Op2,
    unsigned short* __restrict__ Op3,
    float* __restrict__ lp)            // [4][B][N] fp32 l partials
{
    __shared__ __align__(16) unsigned short vs[VSH];         // 32.0 KB [c][kv] swizzled
    __shared__ __align__(16) unsigned short ps[TQ4 * PSS];   // 18.4 KB [q][kv]
    __shared__ float ls[4 * TQ4];                            //  2.0 KB  => 53,248 B

    const int t    = threadIdx.x;
    const int w    = t >> 6;
    const int lane = t & 63;
    const int quad = lane >> 4;
    const int c16  = lane & 15;
    const int flat = blockIdx.x;
    const int quarter = flat & 3;
    const int b    = (flat >> 2) & 3;
    const int q0   = (flat >> 4) * TQ4;
    const int kvb0 = quarter * (N_ / 4);
    // S-phase roles
    const int f   = w & 3;      // kv-tile (16 kv)
    const int qg_ = w >> 2;     // q-half: q-tiles 4qg_..4qg_+3
    // PV roles
    const int cs = w & 3;       // c-stripe (64 c)
    const int pg = w >> 2;      // q-group (64 q)

    const unsigned short* kbase = kg + (size_t)(b * N_) * 32;
    const unsigned short* vbase = vg + (size_t)(b * C_) * N_;

    // hoisted Q B-frags (4 q-tiles per wave)
    short8 bq[4];
#pragma unroll
    for (int g = 0; g < 4; ++g)
        bq[g] = *(const short8*)(qg + ((size_t)(b * N_) + q0 + 16 * (4 * qg_ + g) + c16) * 32 + quad * 8);

    // V DMA mapping (proven R10): wave w stages rows 32w..32w+31, linear LDS dest,
    // pre-swizzled global src so vs[c*TM + 8*j] = V[c][8*(j^(c&7))]
    const int vrow  = lane >> 3;
    const int vslot = lane & 7;
    // K A-frag offset (per wave f, per lane)
    const size_t koff = (size_t)(16 * f + c16) * 32 + quad * 8;

    // prologue: DMA V(0); akpre = K(0). No barrier needed: bar1 of iter 0 drains DMA.
#pragma unroll
    for (int p = 0; p < 4; ++p) {
        const int c = 32 * w + 8 * p + vrow;
        gload_lds16(vbase + (size_t)c * N_ + kvb0 + 8 * (vslot ^ (c & 7)),
                    &vs[(32 * w + 8 * p) * TM]);
    }
    short8 akpre = *(const short8*)(kbase + (size_t)kvb0 * 32 + koff);

    f32x4 O[4][4];
#pragma unroll
    for (int ct = 0; ct < 4; ++ct)
#pragma unroll
        for (int qt = 0; qt < 4; ++qt) O[ct][qt] = (f32x4){0.f, 0.f, 0.f, 0.f};

    float lacc[4] = {0.f, 0.f, 0.f, 0.f};

#pragma unroll 1
    for (int it = 0; it < HIT4W; ++it) {
        // (A) DMA V(it) for it>0 (vs free since bar2 of it-1); S(it) on akpre; reload akpre
        if (it > 0) {
            const int kv0 = kvb0 + it * TM;
#pragma unroll
            for (int p = 0; p < 4; ++p) {
                const int c = 32 * w + 8 * p + vrow;
                gload_lds16(vbase + (size_t)c * N_ + kv0 + 8 * (vslot ^ (c & 7)),
                            &vs[(32 * w + 8 * p) * TM]);
            }
        }

        const f32x4 z = {0.f, 0.f, 0.f, 0.f};
        f32x4 sf[4];
#pragma unroll
        for (int g = 0; g < 4; ++g)
            sf[g] = __builtin_amdgcn_mfma_f32_16x16x32_bf16(akpre, bq[g], z, 0, 0, 0);

        if (it + 1 < HIT4W)
            akpre = *(const short8*)(kbase + (size_t)(kvb0 + (it + 1) * TM) * 32 + koff);

#pragma unroll
        for (int g = 0; g < 4; ++g) {
            float p[4];
#pragma unroll
            for (int r = 0; r < 4; ++r) p[r] = EXP2F(sf[g][r]);
            lacc[g] += (p[0] + p[1]) + (p[2] + p[3]);
            uint2v u;
            u.x = pack2bf(p[0], p[1]);
            u.y = pack2bf(p[2], p[3]);
            *(uint2v*)&ps[(16 * (4 * qg_ + g) + c16) * PSS + f * 16 + 4 * quad] = u;
        }
        __syncthreads();   // bar1: ps visible; V(it) DMA drained (vmcnt 0)

        // (B) PV(it): wave (cs, pg) -> O[64c x 64q]
        short8 bp[4][2];
#pragma unroll
        for (int qt = 0; qt < 4; ++qt)
#pragma unroll
            for (int s = 0; s < 2; ++s)
                bp[qt][s] = *(const short8*)&ps[(64 * pg + 16 * qt + c16) * PSS + 32 * s + 8 * quad];
#pragma unroll
        for (int s = 0; s < 2; ++s)
#pragma unroll
            for (int ct = 0; ct < 4; ++ct) {
                const int c = 64 * cs + 16 * ct + c16;
                const short8 av = *(const short8*)&vs[c * TM + 8 * ((4 * s + quad) ^ (c & 7))];
#pragma unroll
                for (int qt = 0; qt < 4; ++qt)
                    O[ct][qt] = __builtin_amdgcn_mfma_f32_16x16x32_bf16(av, bp[qt][s], O[ct][qt], 0, 0, 0);
            }
        __syncthreads();   // bar2: PV + ps reads done; vs overwrite legal next iter
    }

    // l reduction
#pragma unroll
    for (int g = 0; g < 4; ++g) {
        lacc[g] += __shfl_xor(lacc[g], 16);
        lacc[g] += __shfl_xor(lacc[g], 32);
    }
    if (quad == 0) {
#pragma unroll
        for (int g = 0; g < 4; ++g)
            ls[f * TQ4 + 16 * (4 * qg_ + g) + c16] = lacc[g];
    }
    __syncthreads();

    // store partials
    if (quarter == 0) {
        float* ob = outp + (size_t)(b * C_) * N_;
#pragma unroll
        for (int ct = 0; ct < 4; ++ct)
#pragma unroll
            for (int qt = 0; qt < 4; ++qt) {
                const int n = q0 + 64 * pg + 16 * qt + c16;
#pragma unroll
                for (int r = 0; r < 4; ++r) {
                    const int c = 64 * cs + 16 * ct + 4 * quad + r;
                    ob[(size_t)c * N_ + n] = O[ct][qt][r];
                }
            }
    } else {
        unsigned short* op = (quarter == 1) ? Op1 : (quarter == 2) ? Op2 : Op3;
        unsigned short* ob = op + (size_t)(b * C_) * N_;
#pragma unroll
        for (int ct = 0; ct < 4; ++ct)
#pragma unroll
            for (int qt = 0; qt < 4; ++qt) {
                const int n = q0 + 64 * pg + 16 * qt + c16;
#pragma unroll
                for (int r = 0; r < 4; ++r) {
                    const int c = 64 * cs + 16 * ct + 4 * quad + r;
                    ob[(size_t)c * N_ + n] = f2bf(O[ct][qt][r]);
                }
            }
    }
    if (w == 0) {
#pragma unroll
        for (int h = 0; h < 2; ++h) {
            const int qq = lane + 64 * h;
            const float lv = ls[qq] + ls[TQ4 + qq] + ls[2 * TQ4 + qq] + ls[3 * TQ4 + qq];
            lp[(size_t)(quarter * B_ + b) * N_ + q0 + qq] = lv;
        }
    }
}

// ---------- combine 4-way ----------
__global__ __launch_bounds__(256) void combine4_kernel(
    const float* __restrict__ x,
    const unsigned short* __restrict__ Op1,
    const unsigned short* __restrict__ Op2,
    const unsigned short* __restrict__ Op3,
    const float* __restrict__ lp,
    float* __restrict__ out)
{
    __shared__ float linv[1024];

    const int t  = threadIdx.x;
    const int n0 = blockIdx.x * 1024;
    const int c0 = blockIdx.y * 8;
    const int b  = blockIdx.z;

#pragma unroll
    for (int i = 0; i < 4; ++i) {
        const int n = n0 + t + 256 * i;
        float l = 0.f;
#pragma unroll
        for (int q = 0; q < 4; ++q) l += lp[(size_t)(q * B_ + b) * N_ + n];
        linv[t + 256 * i] = 1.0f / l;
    }
    __syncthreads();

#pragma unroll
    for (int cc = 0; cc < 8; ++cc) {
        const int c = c0 + cc;
        const size_t base = ((size_t)(b * C_) + c) * N_ + n0 + 4 * t;
        const f32x4 o0 = *(const f32x4*)&out[base];
        const short4v a1 = *(const short4v*)&Op1[base];
        const short4v a2 = *(const short4v*)&Op2[base];
        const short4v a3 = *(const short4v*)&Op3[base];
        const f32x4 xv = *(const f32x4*)&x[base];
        f32x4 o;
#pragma unroll
        for (int r = 0; r < 4; ++r) {
            const float s = o0[r] + bf2f((unsigned short)a1[r]) + bf2f((unsigned short)a2[r])
                                  + bf2f((unsigned short)a3[r]);
            o[r] = xv[r] + s * linv[4 * t + r];
        }
        *(f32x4*)&out[base] = o;
    }
}

// ---------- attn 2-way fallback (exact R10, proven) ----------
__global__ __launch_bounds__(512, 4) void attn2_kernel(
    const unsigned short* __restrict__ qg,
    const unsigned short* __restrict__ kg,
    const unsigned short* __restrict__ vg,
    float* __restrict__ outp,
    unsigned short* __restrict__ Op1,
    float* __restrict__ lp)
{
    __shared__ __align__(16) unsigned short vs[2 * VSH];
    __shared__ __align__(16) unsigned short ps[TQ2 * PSS];
    __shared__ float ls[4 * TQ2];

    const int t    = threadIdx.x;
    const int w    = t >> 6;
    const int lane = t & 63;
    const int quad = lane >> 4;
    const int c16  = lane & 15;
    const int flat = blockIdx.x;
    const int half = flat & 1;
    const int b    = (flat >> 1) & 3;
    const int q0   = (flat >> 3) * TQ2;
    const int kvb0 = half * (N_ / 2);
    const int f   = w & 3;
    const int qg_ = w >> 2;
    const int cs = w & 3;
    const int pg = w >> 2;

    const unsigned short* kbase = kg + (size_t)(b * N_) * 32;
    const unsigned short* vbase = vg + (size_t)(b * C_) * N_;

    short8 bq[2];
#pragma unroll
    for (int g = 0; g < 2; ++g)
        bq[g] = *(const short8*)(qg + ((size_t)(b * N_) + q0 + 16 * (2 * qg_ + g) + c16) * 32 + quad * 8);

    const int vrow  = lane >> 3;
    const int vslot = lane & 7;
    const size_t koff = (size_t)(16 * f + c16) * 32 + quad * 8;

#pragma unroll
    for (int p = 0; p < 4; ++p) {
        const int c = 32 * w + 8 * p + vrow;
        gload_lds16(vbase + (size_t)c * N_ + kvb0 + 8 * (vslot ^ (c & 7)),
                    &vs[(32 * w + 8 * p) * TM]);
    }
    short8 akpre = *(const short8*)(kbase + (size_t)kvb0 * 32 + koff);
    __syncthreads();

    f32x4 O[4][2];
#pragma unroll
    for (int ct = 0; ct < 4; ++ct)
#pragma unroll
        for (int qt = 0; qt < 2; ++qt) O[ct][qt] = (f32x4){0.f, 0.f, 0.f, 0.f};

    float lacc[2] = {0.f, 0.f};

#pragma unroll 1
    for (int it = 0; it < HIT2W; ++it) {
        const int cur = it & 1;
        const int nxt = cur ^ 1;

        const f32x4 z = {0.f, 0.f, 0.f, 0.f};
        f32x4 sf[2];
#pragma unroll
        for (int g = 0; g < 2; ++g)
            sf[g] = __builtin_amdgcn_mfma_f32_16x16x32_bf16(akpre, bq[g], z, 0, 0, 0);

#pragma unroll
        for (int g = 0; g < 2; ++g) {
            float p[4];
#pragma unroll
            for (int r = 0; r < 4; ++r) p[r] = EXP2F(sf[g][r]);
            lacc[g] += (p[0] + p[1]) + (p[2] + p[3]);
            uint2v u;
            u.x = pack2bf(p[0], p[1]);
            u.y = pack2bf(p[2], p[3]);
            *(uint2v*)&ps[(16 * (2 * qg_ + g) + c16) * PSS + f * 16 + 4 * quad] = u;
        }
        __syncthreads();

        if (it + 1 < HIT2W) {
            const int kv0n = kvb0 + (it + 1) * TM;
#pragma unroll
            for (int p = 0; p < 4; ++p) {
                const int c = 32 * w + 8 * p + vrow;
                gload_lds16(vbase + (size_t)c * N_ + kv0n + 8 * (vslot ^ (c & 7)),
                            &vs[nxt * VSH + (32 * w + 8 * p) * TM]);
            }
            akpre = *(const short8*)(kbase + (size_t)(kv0n) * 32 + koff);
        }

        short8 bp[2][2];
#pragma unroll
        for (int qt = 0; qt < 2; ++qt)
#pragma unroll
            for (int s = 0; s < 2; ++s)
                bp[qt][s] = *(const short8*)&ps[(32 * pg + 16 * qt + c16) * PSS + 32 * s + 8 * quad];
#pragma unroll
        for (int s = 0; s < 2; ++s)
#pragma unroll
            for (int ct = 0; ct < 4; ++ct) {
                const int c = 64 * cs + 16 * ct + c16;
                const short8 av = *(const short8*)&vs[cur * VSH + c * TM + 8 * ((4 * s + quad) ^ (c & 7))];
#pragma unroll
                for (int qt = 0; qt < 2; ++qt)
                    O[ct][qt] = __builtin_amdgcn_mfma_f32_16x16x32_bf16(av, bp[qt][s], O[ct][qt], 0, 0, 0);
            }
        __syncthreads();
    }

#pragma unroll
    for (int g = 0; g < 2; ++g) {
        lacc[g] += __shfl_xor(lacc[g], 16);
        lacc[g] += __shfl_xor(lacc[g], 32);
    }
    if (quad == 0) {
#pragma unroll
        for (int g = 0; g < 2; ++g)
            ls[f * TQ2 + 16 * (2 * qg_ + g) + c16] = lacc[g];
    }
    __syncthreads();

    if (half == 0) {
        float* ob = outp + (size_t)(b * C_) * N_;
#pragma unroll
        for (int ct = 0; ct < 4; ++ct)
#pragma unroll
            for (int qt = 0; qt < 2; ++qt) {
                const int n = q0 + 32 * pg + 16 * qt + c16;
#pragma unroll
                for (int r = 0; r < 4; ++r) {
                    const int c = 64 * cs + 16 * ct + 4 * quad + r;
                    ob[(size_t)c * N_ + n] = O[ct][qt][r];
                }
            }
    } else {
        unsigned short* ob = Op1 + (size_t)(b * C_) * N_;
#pragma unroll
        for (int ct = 0; ct < 4; ++ct)
#pragma unroll
            for (int qt = 0; qt < 2; ++qt) {
                const int n = q0 + 32 * pg + 16 * qt + c16;
#pragma unroll
                for (int r = 0; r < 4; ++r) {
                    const int c = 64 * cs + 16 * ct + 4 * quad + r;
                    ob[(size_t)c * N_ + n] = f2bf(O[ct][qt][r]);
                }
            }
    }
    if (w == 0) {
        const int qq = lane;
        const float lv = ls[qq] + ls[TQ2 + qq] + ls[2 * TQ2 + qq] + ls[3 * TQ2 + qq];
        lp[(size_t)(half * B_ + b) * N_ + q0 + qq] = lv;
    }
}

// ---------- combine 2-way fallback (exact R10) ----------
__global__ __launch_bounds__(256) void combine2_kernel(
    const float* __restrict__ x,
    const unsigned short* __restrict__ Op1,
    const float* __restrict__ lp,
    float* __restrict__ out)
{
    __shared__ float linv[1024];

    const int t  = threadIdx.x;
    const int n0 = blockIdx.x * 1024;
    const int c0 = blockIdx.y * 8;
    const int b  = blockIdx.z;

#pragma unroll
    for (int i = 0; i < 4; ++i) {
        const int n = n0 + t + 256 * i;
        const float l = lp[(size_t)b * N_ + n] + lp[(size_t)(B_ + b) * N_ + n];
        linv[t + 256 * i] = 1.0f / l;
    }
    __syncthreads();

#pragma unroll
    for (int cc = 0; cc < 8; ++cc) {
        const int c = c0 + cc;
        const size_t base = ((size_t)(b * C_) + c) * N_ + n0 + 4 * t;
        const f32x4 o0 = *(const f32x4*)&out[base];
        const short4v a1 = *(const short4v*)&Op1[base];
        const f32x4 xv = *(const f32x4*)&x[base];
        f32x4 o;
        o.x = xv.x + (o0.x + bf2f((unsigned short)a1[0])) * linv[4 * t + 0];
        o.y = xv.y + (o0.y + bf2f((unsigned short)a1[1])) * linv[4 * t + 1];
        o.z = xv.z + (o0.z + bf2f((unsigned short)a1[2])) * linv[4 * t + 2];
        o.w = xv.w + (o0.w + bf2f((unsigned short)a1[3])) * linv[4 * t + 3];
        *(f32x4*)&out[base] = o;
    }
}

extern "C" void kernel_launch(void* const* d_in, const int* in_sizes, int n_in,
                              void* d_out, int out_size, void* d_ws, size_t ws_size,
                              hipStream_t stream) {
    const float* x  = (const float*)d_in[0];
    const float* Wq = (const float*)d_in[1];
    const float* bq = (const float*)d_in[2];
    const float* Wk = (const float*)d_in[3];
    const float* bk = (const float*)d_in[4];
    const float* Wv = (const float*)d_in[5];
    const float* bv = (const float*)d_in[6];
    float* out = (float*)d_out;

    const size_t SZ_QKB = (size_t)B_ * N_ * 32;     // shorts, 1 MB each
    const size_t SZ_CN  = (size_t)B_ * C_ * N_;     // shorts, 8 MB

    unsigned short* ws16 = (unsigned short*)d_ws;
    unsigned short* qb  = ws16;
    unsigned short* kb  = qb + SZ_QKB;
    unsigned short* vb  = kb + SZ_QKB;
    unsigned short* Op1 = vb + SZ_CN;
    unsigned short* Op2 = Op1 + SZ_CN;
    unsigned short* Op3 = Op2 + SZ_CN;
    // 4-way tail: wbf/biasf/lp after Op3; 2-way tail: after Op1
    const size_t need4 = (2 * SZ_QKB + 4 * SZ_CN + 320 * C_) * 2 + 320 * 4 + (size_t)4 * B_ * N_ * 4 + 1024;

    if (ws_size >= need4) {
        unsigned short* wbf = Op3 + SZ_CN;
        float* biasf = (float*)(wbf + 320 * C_);
        float* lpp   = biasf + 320;                  // [4][B][N]
        cvt_w<<<dim3(320), 256, 0, stream>>>(Wq, bq, Wk, bk, Wv, bv, wbf, biasf);
        proj_qkv<<<dim3(N_ / 32, B_), 256, 0, stream>>>(x, wbf, biasf, qb, kb, vb);
        attn4_kernel<<<dim3(512), 512, 0, stream>>>(qb, kb, vb, out, Op1, Op2, Op3, lpp);
        combine4_kernel<<<dim3(4, 32, B_), 256, 0, stream>>>(x, Op1, Op2, Op3, lpp, out);
    } else {
        unsigned short* wbf = Op1 + SZ_CN;
        float* biasf = (float*)(wbf + 320 * C_);
        float* lpp   = biasf + 320;                  // [2][B][N]
        cvt_w<<<dim3(320), 256, 0, stream>>>(Wq, bq, Wk, bk, Wv, bv, wbf, biasf);
        proj_qkv<<<dim3(N_ / 32, B_), 256, 0, stream>>>(x, wbf, biasf, qb, kb, vb);
        attn2_kernel<<<dim3(512), 512, 0, stream>>>(qb, kb, vb, out, Op1, lpp);
        combine2_kernel<<<dim3(4, 32, B_), 256, 0, stream>>>(x, Op1, lpp, out);
    }
}

// Round 12
// 149.916 us; speedup vs baseline: 1.0533x; 1.0533x over previous
//
#include <hip/hip_runtime.h>
#include <math.h>

#define B_   4
#define C_   256
#define CQK  32
#define N_   4096
#define TQ   64           // q per attn block
#define TM   64           // kv per chunk
#define HITERS ((N_ / 2) / TM)   // 32 chunks per kv-half
#define PSS  72           // ps row stride (shorts)
#define VSH  (C_ * TM)    // one vs buffer: 16384 shorts (32 KB)
#define XT2  264          // proj xT row stride (shorts): 256 + 8 pad
#define VOS  40           // proj vout row stride (shorts): 32 + 8 pad

typedef __attribute__((ext_vector_type(8))) short short8;
typedef __attribute__((ext_vector_type(4))) short short4v;
typedef __attribute__((ext_vector_type(4))) float f32x4;
typedef __attribute__((ext_vector_type(2))) unsigned int uint2v;

#if __has_builtin(__builtin_amdgcn_exp2f)
#define EXP2F(x) __builtin_amdgcn_exp2f(x)
#else
#define EXP2F(x) exp2f(x)
#endif

// global -> LDS direct DMA, 16B per lane; LDS dest is wave-uniform base + lane*16
typedef const __attribute__((address_space(1))) unsigned int* gas1_t;
typedef __attribute__((address_space(3))) unsigned int* las3_t;
__device__ __forceinline__ void gload_lds16(const unsigned short* g, unsigned short* l) {
    __builtin_amdgcn_global_load_lds((gas1_t)g, (las3_t)l, 16, 0, 0);
}

__device__ __forceinline__ unsigned short f2bf(float f) {
    unsigned u = __builtin_bit_cast(unsigned, f);
    u += 0x7fffu + ((u >> 16) & 1u);
    return (unsigned short)(u >> 16);
}
__device__ __forceinline__ float bf2f(unsigned short s) {
    return __builtin_bit_cast(float, (unsigned)s << 16);
}
__device__ __forceinline__ unsigned pack2bf(float a, float b) {
    unsigned ua = __builtin_bit_cast(unsigned, a) + 0x8000u;
    unsigned ub = __builtin_bit_cast(unsigned, b) + 0x8000u;
#if __has_builtin(__builtin_amdgcn_perm)
    return __builtin_amdgcn_perm(ub, ua, 0x07060302u);
#else
    return (ua >> 16) | (ub & 0xffff0000u);
#endif
}

// ---------- weights -> bf16 [320][256] + fp32 bias[320]; log2e folded into q ----------
__global__ __launch_bounds__(256) void cvt_w(
    const float* __restrict__ Wq, const float* __restrict__ bq,
    const float* __restrict__ Wk, const float* __restrict__ bk,
    const float* __restrict__ Wv, const float* __restrict__ bv,
    unsigned short* __restrict__ wbf, float* __restrict__ biasf)
{
    const float LOG2E = 1.4426950408889634f;
    const int r = blockIdx.x;   // 0..319
    const int t = threadIdx.x;
    const float* src = (r < 32) ? (Wq + r * C_)
                     : (r < 64) ? (Wk + (r - 32) * C_)
                                : (Wv + (r - 64) * C_);
    const float scale = (r < 32) ? LOG2E : 1.0f;
    wbf[r * C_ + t] = f2bf(src[t] * scale);
    if (t == 0)
        biasf[r] = (r < 32) ? bq[r] * LOG2E : (r < 64) ? bk[r - 32] : bv[r - 64];
}

// ---------- fused qkv projection v2: 512 blocks (2/CU), vectorized staging + stores ----------
__global__ __launch_bounds__(256, 2) void proj_qkv(
    const float* __restrict__ x, const unsigned short* __restrict__ wbf,
    const float* __restrict__ biasf,
    unsigned short* __restrict__ qb, unsigned short* __restrict__ kb,
    unsigned short* __restrict__ vb)
{
    __shared__ __align__(16) unsigned short xT[32 * XT2];
    __shared__ __align__(16) unsigned short vout[256 * VOS];
    __shared__ __align__(16) unsigned short qks[32 * 72];

    const int t    = threadIdx.x;
    const int w    = t >> 6;
    const int lane = t & 63;
    const int quad = lane >> 4;
    const int c16  = lane & 15;
    const int n0   = blockIdx.x * 32;
    const int b    = blockIdx.y;

    {
        const int c0 = (t >> 3) * 8;
        const int nq = t & 7;
        f32x4 xv[8];
#pragma unroll
        for (int i = 0; i < 8; ++i)
            xv[i] = *(const f32x4*)&x[((size_t)(b * C_) + c0 + i) * N_ + n0 + 4 * nq];
#pragma unroll
        for (int j = 0; j < 4; ++j) {
            short8 pk;
#pragma unroll
            for (int i = 0; i < 8; ++i) pk[i] = (short)f2bf(xv[i][j]);
            *(short8*)&xT[(4 * nq + j) * XT2 + c0] = pk;
        }
    }
    __syncthreads();

    f32x4 acc[5][2];
#pragma unroll
    for (int i = 0; i < 5; ++i)
#pragma unroll
        for (int nt = 0; nt < 2; ++nt) acc[i][nt] = (f32x4){0.f, 0.f, 0.f, 0.f};

    const unsigned short* wr = wbf + (size_t)(80 * w + c16) * C_ + quad * 8;

#pragma unroll
    for (int ks = 0; ks < 8; ++ks) {
        short8 af[5], bf[2];
#pragma unroll
        for (int i = 0; i < 5; ++i)
            af[i] = *(const short8*)(wr + (size_t)(16 * i) * C_ + 32 * ks);
#pragma unroll
        for (int nt = 0; nt < 2; ++nt)
            bf[nt] = *(const short8*)&xT[(16 * nt + c16) * XT2 + ks * 32 + quad * 8];
#pragma unroll
        for (int i = 0; i < 5; ++i)
#pragma unroll
            for (int nt = 0; nt < 2; ++nt)
                acc[i][nt] = __builtin_amdgcn_mfma_f32_16x16x32_bf16(af[i], bf[nt], acc[i][nt], 0, 0, 0);
    }

#pragma unroll
    for (int i = 0; i < 5; ++i) {
        const int OT = 5 * w + i;
        const int obase = OT * 16 + 4 * quad;
        const f32x4 bv4 = *(const f32x4*)&biasf[obase];
#pragma unroll
        for (int nt = 0; nt < 2; ++nt) {
            const int n = 16 * nt + c16;
            float vals[4];
#pragma unroll
            for (int r = 0; r < 4; ++r) vals[r] = acc[i][nt][r] + bv4[r];
            if (OT >= 4) {
#pragma unroll
                for (int r = 0; r < 4; ++r)
                    vout[(obase + r - 64) * VOS + n] = f2bf(vals[r]);
            } else {
                const int col = (OT < 2 ? 0 : 32) + (OT & 1) * 16 + 4 * quad;
                short4v pk;
#pragma unroll
                for (int r = 0; r < 4; ++r) pk[r] = (short)f2bf(vals[r]);
                *(short4v*)&qks[n * 72 + col] = pk;
            }
        }
    }
    __syncthreads();

#pragma unroll
    for (int p = 0; p < 4; ++p) {
        const int c   = 64 * p + (t >> 2);
        const int seg = t & 3;
        const short8 vv = *(const short8*)&vout[c * VOS + seg * 8];
        *(short8*)(vb + ((size_t)(b * C_) + c) * N_ + n0 + seg * 8) = vv;
    }
    if (w < 2) {
        unsigned short* dst = w ? kb : qb;
        const int coff = w ? 32 : 0;
#pragma unroll
        for (int h = 0; h < 2; ++h) {
            const int n = 16 * h + (lane >> 2);
            const int c = (lane & 3) * 8;
            const short8 v = *(const short8*)&qks[n * 72 + coff + c];
            *(short8*)(dst + ((size_t)(b * N_) + n0 + n) * 32 + c) = v;
        }
    }
}

// ---------- flash attention: 4 waves, 64c x 64q per-wave PV tile, split-kv 2-way ----------
// R10 pipeline preserved: double-buffered V via global_load_lds DMA (issued after bar1,
// drained by bar2's vmcnt), K in regs, 2 barriers/iter, 512 blocks (2 blocks/CU).
// grid 512 x 256thr: half = flat&1, b = (flat>>1)&3, q0 = (flat>>3)*64
// S-phase: wave w = kv-tile w, all 4 q-tiles. PV: wave w = c-stripe 64w, all 64 q.
__global__ __launch_bounds__(256, 2) void attn_kernel(
    const unsigned short* __restrict__ qg,
    const unsigned short* __restrict__ kg,
    const unsigned short* __restrict__ vg,
    float* __restrict__ outp,          // [B][C][N] fp32 partial (half 0)
    unsigned short* __restrict__ Op1,  // [B][C][N] bf16 partial (half 1)
    float* __restrict__ lp)            // [2][B][N] fp32 l partials
{
    __shared__ __align__(16) unsigned short vs[2 * VSH];    // 64.0 KB 2x [c][kv] swizzled
    __shared__ __align__(16) unsigned short ps[TQ * PSS];   //  9.2 KB [q][kv]
    __shared__ float ls[4 * TQ];                            //  1.0 KB  => 75,776 B

    const int t    = threadIdx.x;
    const int w    = t >> 6;        // 0..3: kv-tile (S) / c-stripe (PV)
    const int lane = t & 63;
    const int quad = lane >> 4;
    const int c16  = lane & 15;
    const int flat = blockIdx.x;
    const int half = flat & 1;
    const int b    = (flat >> 1) & 3;
    const int q0   = (flat >> 3) * TQ;
    const int kvb0 = half * (N_ / 2);

    const unsigned short* kbase = kg + (size_t)(b * N_) * 32;
    const unsigned short* vbase = vg + (size_t)(b * C_) * N_;

    // hoisted Q B-frags: all 4 q-tiles
    short8 bq[4];
#pragma unroll
    for (int g = 0; g < 4; ++g)
        bq[g] = *(const short8*)(qg + ((size_t)(b * N_) + q0 + 16 * g + c16) * 32 + quad * 8);

    // V DMA mapping: wave w stages rows 64w..64w+63 in 8 instrs of 8 rows (1 KB each).
    // LDS dest linear; global src pre-swizzled: vs[c*TM + 8*j] = V[c][8*(j^(c&7))]
    const int vrow  = lane >> 3;   // 0..7
    const int vslot = lane & 7;
    // K A-frag offset (per wave = kv-tile w)
    const size_t koff = (size_t)(16 * w + c16) * 32 + quad * 8;

    // prologue: DMA V(0) into buf 0; akpre = K(0)
#pragma unroll
    for (int p = 0; p < 8; ++p) {
        const int c = 64 * w + 8 * p + vrow;
        gload_lds16(vbase + (size_t)c * N_ + kvb0 + 8 * (vslot ^ (c & 7)),
                    &vs[(64 * w + 8 * p) * TM]);
    }
    short8 akpre = *(const short8*)(kbase + (size_t)kvb0 * 32 + koff);
    __syncthreads();   // V(0) DMA drained + visible

    f32x4 O[4][4];
#pragma unroll
    for (int ct = 0; ct < 4; ++ct)
#pragma unroll
        for (int qt = 0; qt < 4; ++qt) O[ct][qt] = (f32x4){0.f, 0.f, 0.f, 0.f};

    float lacc[4] = {0.f, 0.f, 0.f, 0.f};

#pragma unroll 1
    for (int it = 0; it < HITERS; ++it) {
        const int cur = it & 1;
        const int nxt = cur ^ 1;

        // (1) S^T = K.Q^T : kv-tile w x 4 q-tiles (K(it) in akpre)
        const f32x4 z = {0.f, 0.f, 0.f, 0.f};
        f32x4 sf[4];
#pragma unroll
        for (int g = 0; g < 4; ++g)
            sf[g] = __builtin_amdgcn_mfma_f32_16x16x32_bf16(akpre, bq[g], z, 0, 0, 0);

#pragma unroll
        for (int g = 0; g < 4; ++g) {
            float p[4];
#pragma unroll
            for (int r = 0; r < 4; ++r) p[r] = EXP2F(sf[g][r]);
            lacc[g] += (p[0] + p[1]) + (p[2] + p[3]);
            uint2v u;
            u.x = pack2bf(p[0], p[1]);
            u.y = pack2bf(p[2], p[3]);
            *(uint2v*)&ps[(16 * g + c16) * PSS + w * 16 + 4 * quad] = u;
        }
        __syncthreads();   // bar1: ps visible; vs[nxt] reads (PV it-1) done

        // (2) issue V(it+1) DMA into vs[nxt]; prefetch K(it+1) A-frag.
        //     Drained by bar2's vmcnt, hidden under PV.
        if (it + 1 < HITERS) {
            const int kv0n = kvb0 + (it + 1) * TM;
#pragma unroll
            for (int p = 0; p < 8; ++p) {
                const int c = 64 * w + 8 * p + vrow;
                gload_lds16(vbase + (size_t)c * N_ + kv0n + 8 * (vslot ^ (c & 7)),
                            &vs[nxt * VSH + (64 * w + 8 * p) * TM]);
            }
            akpre = *(const short8*)(kbase + (size_t)kv0n * 32 + koff);
        }

        // (3) PV on buffer cur: wave w -> O[64c x 64q]
        short8 bp[4][2];
#pragma unroll
        for (int qt = 0; qt < 4; ++qt)
#pragma unroll
            for (int s = 0; s < 2; ++s)
                bp[qt][s] = *(const short8*)&ps[(16 * qt + c16) * PSS + 32 * s + 8 * quad];
#pragma unroll
        for (int s = 0; s < 2; ++s)
#pragma unroll
            for (int ct = 0; ct < 4; ++ct) {
                const int c = 64 * w + 16 * ct + c16;
                const short8 av = *(const short8*)&vs[cur * VSH + c * TM + 8 * ((4 * s + quad) ^ (c & 7))];
#pragma unroll
                for (int qt = 0; qt < 4; ++qt)
                    O[ct][qt] = __builtin_amdgcn_mfma_f32_16x16x32_bf16(av, bp[qt][s], O[ct][qt], 0, 0, 0);
            }
        __syncthreads();   // bar2: PV + ps reads done; V(it+1) DMA drained
    }

    // l reduction: quad-sum (shfl) then across the 4 kv-tile waves (LDS)
#pragma unroll
    for (int g = 0; g < 4; ++g) {
        lacc[g] += __shfl_xor(lacc[g], 16);
        lacc[g] += __shfl_xor(lacc[g], 32);
    }
    if (quad == 0) {
#pragma unroll
        for (int g = 0; g < 4; ++g)
            ls[w * TQ + 16 * g + c16] = lacc[g];
    }
    __syncthreads();

    // store partials: half 0 -> fp32 into outp; half 1 -> bf16 into Op1
    if (half == 0) {
        float* ob = outp + (size_t)(b * C_) * N_;
#pragma unroll
        for (int ct = 0; ct < 4; ++ct)
#pragma unroll
            for (int qt = 0; qt < 4; ++qt) {
                const int n = q0 + 16 * qt + c16;
#pragma unroll
                for (int r = 0; r < 4; ++r) {
                    const int c = 64 * w + 16 * ct + 4 * quad + r;
                    ob[(size_t)c * N_ + n] = O[ct][qt][r];
                }
            }
    } else {
        unsigned short* ob = Op1 + (size_t)(b * C_) * N_;
#pragma unroll
        for (int ct = 0; ct < 4; ++ct)
#pragma unroll
            for (int qt = 0; qt < 4; ++qt) {
                const int n = q0 + 16 * qt + c16;
#pragma unroll
                for (int r = 0; r < 4; ++r) {
                    const int c = 64 * w + 16 * ct + 4 * quad + r;
                    ob[(size_t)c * N_ + n] = f2bf(O[ct][qt][r]);
                }
            }
    }
    if (w == 0) {
        const int qq = lane;
        const float lv = ls[qq] + ls[TQ + qq] + ls[2 * TQ + qq] + ls[3 * TQ + qq];
        lp[(size_t)(half * B_ + b) * N_ + q0 + qq] = lv;
    }
}

// ---------- combine: out = x + (O0(out) + O1) / (l0 + l1), in place ----------
__global__ __launch_bounds__(256) void combine_kernel(
    const float* __restrict__ x,
    const unsigned short* __restrict__ Op1,
    const float* __restrict__ lp,
    float* __restrict__ out)
{
    __shared__ float linv[1024];

    const int t  = threadIdx.x;
    const int n0 = blockIdx.x * 1024;
    const int c0 = blockIdx.y * 8;
    const int b  = blockIdx.z;

#pragma unroll
    for (int i = 0; i < 4; ++i) {
        const int n = n0 + t + 256 * i;
        const float l = lp[(size_t)b * N_ + n] + lp[(size_t)(B_ + b) * N_ + n];
        linv[t + 256 * i] = 1.0f / l;
    }
    __syncthreads();

#pragma unroll
    for (int cc = 0; cc < 8; ++cc) {
        const int c = c0 + cc;
        const size_t base = ((size_t)(b * C_) + c) * N_ + n0 + 4 * t;
        const f32x4 o0 = *(const f32x4*)&out[base];
        const short4v a1 = *(const short4v*)&Op1[base];
        const f32x4 xv = *(const f32x4*)&x[base];
        f32x4 o;
        o.x = xv.x + (o0.x + bf2f((unsigned short)a1[0])) * linv[4 * t + 0];
        o.y = xv.y + (o0.y + bf2f((unsigned short)a1[1])) * linv[4 * t + 1];
        o.z = xv.z + (o0.z + bf2f((unsigned short)a1[2])) * linv[4 * t + 2];
        o.w = xv.w + (o0.w + bf2f((unsigned short)a1[3])) * linv[4 * t + 3];
        *(f32x4*)&out[base] = o;
    }
}

extern "C" void kernel_launch(void* const* d_in, const int* in_sizes, int n_in,
                              void* d_out, int out_size, void* d_ws, size_t ws_size,
                              hipStream_t stream) {
    const float* x  = (const float*)d_in[0];
    const float* Wq = (const float*)d_in[1];
    const float* bq = (const float*)d_in[2];
    const float* Wk = (const float*)d_in[3];
    const float* bk = (const float*)d_in[4];
    const float* Wv = (const float*)d_in[5];
    const float* bv = (const float*)d_in[6];
    float* out = (float*)d_out;

    unsigned short* ws16 = (unsigned short*)d_ws;
    unsigned short* qb  = ws16;                              // [B][N][32]   1 MB
    unsigned short* kb  = qb + (size_t)B_ * N_ * 32;         // [B][N][32]   1 MB
    unsigned short* vb  = kb + (size_t)B_ * N_ * 32;         // [B][C][N]    8 MB
    unsigned short* Op1 = vb + (size_t)B_ * C_ * N_;         // [B][C][N]    8 MB (bf16 partial, half 1)
    unsigned short* wbf = Op1 + (size_t)B_ * C_ * N_;        // [320][256]   160 KB
    float* biasf = (float*)(wbf + 320 * C_);                 // [320]
    float* lpp   = biasf + 320;                              // [2][B][N]    128 KB

    cvt_w<<<dim3(320), 256, 0, stream>>>(Wq, bq, Wk, bk, Wv, bv, wbf, biasf);
    proj_qkv<<<dim3(N_ / 32, B_), 256, 0, stream>>>(x, wbf, biasf, qb, kb, vb);
    attn_kernel<<<dim3(512), 256, 0, stream>>>(qb, kb, vb, out, Op1, lpp);
    combine_kernel<<<dim3(4, 32, B_), 256, 0, stream>>>(x, Op1, lpp, out);
}

// Round 13
// 144.932 us; speedup vs baseline: 1.0895x; 1.0344x over previous
//
#include <hip/hip_runtime.h>
#include <math.h>

#define B_   4
#define C_   256
#define CQK  32
#define N_   4096
#define TQ   64           // q per attn block (512 blocks -> 2 blocks/CU)
#define TM   64           // kv per chunk
#define HITERS ((N_ / 2) / TM)   // 32 chunks per kv-half
#define PSS  72           // ps row stride (shorts)
#define VSH  (C_ * TM)    // one vs buffer: 16384 shorts (32 KB)
#define XT2  264          // proj xT row stride (shorts): 256 + 8 pad
#define VOS  40           // proj vout row stride (shorts): 32 + 8 pad

typedef __attribute__((ext_vector_type(8))) short short8;
typedef __attribute__((ext_vector_type(4))) short short4v;
typedef __attribute__((ext_vector_type(4))) float f32x4;
typedef __attribute__((ext_vector_type(2))) unsigned int uint2v;

#if __has_builtin(__builtin_amdgcn_exp2f)
#define EXP2F(x) __builtin_amdgcn_exp2f(x)
#else
#define EXP2F(x) exp2f(x)
#endif

// global -> LDS direct DMA, 16B per lane; LDS dest is wave-uniform base + lane*16
typedef const __attribute__((address_space(1))) unsigned int* gas1_t;
typedef __attribute__((address_space(3))) unsigned int* las3_t;
__device__ __forceinline__ void gload_lds16(const unsigned short* g, unsigned short* l) {
    __builtin_amdgcn_global_load_lds((gas1_t)g, (las3_t)l, 16, 0, 0);
}

__device__ __forceinline__ unsigned short f2bf(float f) {
    unsigned u = __builtin_bit_cast(unsigned, f);
    u += 0x7fffu + ((u >> 16) & 1u);
    return (unsigned short)(u >> 16);
}
__device__ __forceinline__ float bf2f(unsigned short s) {
    return __builtin_bit_cast(float, (unsigned)s << 16);
}
__device__ __forceinline__ unsigned pack2bf(float a, float b) {
    unsigned ua = __builtin_bit_cast(unsigned, a) + 0x8000u;
    unsigned ub = __builtin_bit_cast(unsigned, b) + 0x8000u;
#if __has_builtin(__builtin_amdgcn_perm)
    return __builtin_amdgcn_perm(ub, ua, 0x07060302u);
#else
    return (ua >> 16) | (ub & 0xffff0000u);
#endif
}

// ---------- weights -> bf16 [320][256] + fp32 bias[320]; log2e folded into q ----------
__global__ __launch_bounds__(256) void cvt_w(
    const float* __restrict__ Wq, const float* __restrict__ bq,
    const float* __restrict__ Wk, const float* __restrict__ bk,
    const float* __restrict__ Wv, const float* __restrict__ bv,
    unsigned short* __restrict__ wbf, float* __restrict__ biasf)
{
    const float LOG2E = 1.4426950408889634f;
    const int r = blockIdx.x;   // 0..319
    const int t = threadIdx.x;
    const float* src = (r < 32) ? (Wq + r * C_)
                     : (r < 64) ? (Wk + (r - 32) * C_)
                                : (Wv + (r - 64) * C_);
    const float scale = (r < 32) ? LOG2E : 1.0f;
    wbf[r * C_ + t] = f2bf(src[t] * scale);
    if (t == 0)
        biasf[r] = (r < 32) ? bq[r] * LOG2E : (r < 64) ? bk[r - 32] : bv[r - 64];
}

// ---------- fused qkv projection v2: 512 blocks (2/CU), vectorized staging + stores ----------
__global__ __launch_bounds__(256, 2) void proj_qkv(
    const float* __restrict__ x, const unsigned short* __restrict__ wbf,
    const float* __restrict__ biasf,
    unsigned short* __restrict__ qb, unsigned short* __restrict__ kb,
    unsigned short* __restrict__ vb)
{
    __shared__ __align__(16) unsigned short xT[32 * XT2];
    __shared__ __align__(16) unsigned short vout[256 * VOS];
    __shared__ __align__(16) unsigned short qks[32 * 72];

    const int t    = threadIdx.x;
    const int w    = t >> 6;
    const int lane = t & 63;
    const int quad = lane >> 4;
    const int c16  = lane & 15;
    const int n0   = blockIdx.x * 32;
    const int b    = blockIdx.y;

    {
        const int c0 = (t >> 3) * 8;
        const int nq = t & 7;
        f32x4 xv[8];
#pragma unroll
        for (int i = 0; i < 8; ++i)
            xv[i] = *(const f32x4*)&x[((size_t)(b * C_) + c0 + i) * N_ + n0 + 4 * nq];
#pragma unroll
        for (int j = 0; j < 4; ++j) {
            short8 pk;
#pragma unroll
            for (int i = 0; i < 8; ++i) pk[i] = (short)f2bf(xv[i][j]);
            *(short8*)&xT[(4 * nq + j) * XT2 + c0] = pk;
        }
    }
    __syncthreads();

    f32x4 acc[5][2];
#pragma unroll
    for (int i = 0; i < 5; ++i)
#pragma unroll
        for (int nt = 0; nt < 2; ++nt) acc[i][nt] = (f32x4){0.f, 0.f, 0.f, 0.f};

    const unsigned short* wr = wbf + (size_t)(80 * w + c16) * C_ + quad * 8;

#pragma unroll
    for (int ks = 0; ks < 8; ++ks) {
        short8 af[5], bf[2];
#pragma unroll
        for (int i = 0; i < 5; ++i)
            af[i] = *(const short8*)(wr + (size_t)(16 * i) * C_ + 32 * ks);
#pragma unroll
        for (int nt = 0; nt < 2; ++nt)
            bf[nt] = *(const short8*)&xT[(16 * nt + c16) * XT2 + ks * 32 + quad * 8];
#pragma unroll
        for (int i = 0; i < 5; ++i)
#pragma unroll
            for (int nt = 0; nt < 2; ++nt)
                acc[i][nt] = __builtin_amdgcn_mfma_f32_16x16x32_bf16(af[i], bf[nt], acc[i][nt], 0, 0, 0);
    }

#pragma unroll
    for (int i = 0; i < 5; ++i) {
        const int OT = 5 * w + i;
        const int obase = OT * 16 + 4 * quad;
        const f32x4 bv4 = *(const f32x4*)&biasf[obase];
#pragma unroll
        for (int nt = 0; nt < 2; ++nt) {
            const int n = 16 * nt + c16;
            float vals[4];
#pragma unroll
            for (int r = 0; r < 4; ++r) vals[r] = acc[i][nt][r] + bv4[r];
            if (OT >= 4) {
#pragma unroll
                for (int r = 0; r < 4; ++r)
                    vout[(obase + r - 64) * VOS + n] = f2bf(vals[r]);
            } else {
                const int col = (OT < 2 ? 0 : 32) + (OT & 1) * 16 + 4 * quad;
                short4v pk;
#pragma unroll
                for (int r = 0; r < 4; ++r) pk[r] = (short)f2bf(vals[r]);
                *(short4v*)&qks[n * 72 + col] = pk;
            }
        }
    }
    __syncthreads();

#pragma unroll
    for (int p = 0; p < 4; ++p) {
        const int c   = 64 * p + (t >> 2);
        const int seg = t & 3;
        const short8 vv = *(const short8*)&vout[c * VOS + seg * 8];
        *(short8*)(vb + ((size_t)(b * C_) + c) * N_ + n0 + seg * 8) = vv;
    }
    if (w < 2) {
        unsigned short* dst = w ? kb : qb;
        const int coff = w ? 32 : 0;
#pragma unroll
        for (int h = 0; h < 2; ++h) {
            const int n = 16 * h + (lane >> 2);
            const int c = (lane & 3) * 8;
            const short8 v = *(const short8*)&qks[n * 72 + coff + c];
            *(short8*)(dst + ((size_t)(b * N_) + n0 + n) * 32 + c) = v;
        }
    }
}

// ---------- flash attention: R10 structure (proven 51.9 us) + setprio around PV MFMA ----------
// TQ=64, TM=64, split-kv 2-way, 512 blocks (2 blocks/CU, 16 waves/CU).
// V double-buffered via global_load_lds DMA (issued after bar1, drained by bar2's vmcnt);
// K never in LDS (per-wave A-frag from L2, reg-prefetched); 2 barriers/iter.
// grid 512: half = flat&1, b = (flat>>1)&3, q0 = (flat>>3)*64 (XCD-affine in (half,b))
__global__ __launch_bounds__(512, 4) void attn_kernel(
    const unsigned short* __restrict__ qg,
    const unsigned short* __restrict__ kg,
    const unsigned short* __restrict__ vg,
    float* __restrict__ outp,          // [B][C][N] fp32 partial (half 0)
    unsigned short* __restrict__ Op1,  // [B][C][N] bf16 partial (half 1)
    float* __restrict__ lp)            // [2][B][N] fp32 l partials
{
    __shared__ __align__(16) unsigned short vs[2 * VSH];    // 64.0 KB 2x [c][kv] swizzled
    __shared__ __align__(16) unsigned short ps[TQ * PSS];   //  9.2 KB [q][kv]
    __shared__ float ls[4 * TQ];                            //  1.0 KB   => 75,776 B total

    const int t    = threadIdx.x;
    const int w    = t >> 6;
    const int lane = t & 63;
    const int quad = lane >> 4;
    const int c16  = lane & 15;
    const int flat = blockIdx.x;
    const int half = flat & 1;
    const int b    = (flat >> 1) & 3;
    const int q0   = (flat >> 3) * TQ;
    const int kvb0 = half * (N_ / 2);
    // S-phase roles
    const int f   = w & 3;      // kv-tile
    const int qg_ = w >> 2;     // q-group: q-tiles 2qg_, 2qg_+1
    // PV roles
    const int cs = w & 3;       // c-stripe (64 c)
    const int pg = w >> 2;      // q-group (32 q)

    const unsigned short* kbase = kg + (size_t)(b * N_) * 32;
    const unsigned short* vbase = vg + (size_t)(b * C_) * N_;

    // hoisted Q B-frags
    short8 bq[2];
#pragma unroll
    for (int g = 0; g < 2; ++g)
        bq[g] = *(const short8*)(qg + ((size_t)(b * N_) + q0 + 16 * (2 * qg_ + g) + c16) * 32 + quad * 8);

    // V DMA mapping: wave w stages rows 32w..32w+31 in 4 instrs of 8 rows (1 KB each).
    // LDS dest linear (base + lane*16); global src pre-swizzled so that
    // vs[c*TM + 8*j] holds V[c][8*(j^(c&7))..+7]
    const int vrow  = lane >> 3;   // 0..7
    const int vslot = lane & 7;    // 16B slot within 128B row

    // K A-frag global offset (per wave f, per lane): 16 rows x 64B, L2-hot
    const size_t koff = (size_t)(16 * f + c16) * 32 + quad * 8;

    // prologue: V(0) via DMA into buf 0; akpre = K(0)
#pragma unroll
    for (int p = 0; p < 4; ++p) {
        const int c = 32 * w + 8 * p + vrow;
        gload_lds16(vbase + (size_t)c * N_ + kvb0 + 8 * (vslot ^ (c & 7)),
                    &vs[(32 * w + 8 * p) * TM]);
    }
    short8 akpre = *(const short8*)(kbase + (size_t)kvb0 * 32 + koff);
    __syncthreads();   // V(0) DMA drained + visible

    f32x4 O[4][2];
#pragma unroll
    for (int ct = 0; ct < 4; ++ct)
#pragma unroll
        for (int qt = 0; qt < 2; ++qt) O[ct][qt] = (f32x4){0.f, 0.f, 0.f, 0.f};

    float lacc[2] = {0.f, 0.f};

#pragma unroll 1
    for (int it = 0; it < HITERS; ++it) {
        const int cur = it & 1;
        const int nxt = cur ^ 1;

        // (1) S^T = K.Q^T for 2 q-tiles (K(it) already in akpre)
        const f32x4 z = {0.f, 0.f, 0.f, 0.f};
        f32x4 sf[2];
#pragma unroll
        for (int g = 0; g < 2; ++g)
            sf[g] = __builtin_amdgcn_mfma_f32_16x16x32_bf16(akpre, bq[g], z, 0, 0, 0);

#pragma unroll
        for (int g = 0; g < 2; ++g) {
            float p[4];
#pragma unroll
            for (int r = 0; r < 4; ++r) p[r] = EXP2F(sf[g][r]);
            lacc[g] += (p[0] + p[1]) + (p[2] + p[3]);
            uint2v u;
            u.x = pack2bf(p[0], p[1]);
            u.y = pack2bf(p[2], p[3]);
            *(uint2v*)&ps[(16 * (2 * qg_ + g) + c16) * PSS + f * 16 + 4 * quad] = u;
        }
        __syncthreads();   // bar1: ps visible; vs[nxt] reads (PV it-1) long done

        // (2) issue V(it+1) DMA into vs[nxt]; prefetch K(it+1) A-frag into regs.
        //     Both complete by bar2's vmcnt drain, hidden under PV.
        if (it + 1 < HITERS) {
            const int kv0n = kvb0 + (it + 1) * TM;
#pragma unroll
            for (int p = 0; p < 4; ++p) {
                const int c = 32 * w + 8 * p + vrow;
                gload_lds16(vbase + (size_t)c * N_ + kv0n + 8 * (vslot ^ (c & 7)),
                            &vs[nxt * VSH + (32 * w + 8 * p) * TM]);
            }
            akpre = *(const short8*)(kbase + (size_t)kv0n * 32 + koff);
        }

        // (3) PV on buffer cur — setprio(1) keeps the matrix pipe fed while the
        //     co-resident block (at a different phase) issues DMA/exp work
        short8 bp[2][2];
#pragma unroll
        for (int qt = 0; qt < 2; ++qt)
#pragma unroll
            for (int s = 0; s < 2; ++s)
                bp[qt][s] = *(const short8*)&ps[(32 * pg + 16 * qt + c16) * PSS + 32 * s + 8 * quad];
        __builtin_amdgcn_s_setprio(1);
#pragma unroll
        for (int s = 0; s < 2; ++s)
#pragma unroll
            for (int ct = 0; ct < 4; ++ct) {
                const int c = 64 * cs + 16 * ct + c16;
                const short8 av = *(const short8*)&vs[cur * VSH + c * TM + 8 * ((4 * s + quad) ^ (c & 7))];
#pragma unroll
                for (int qt = 0; qt < 2; ++qt)
                    O[ct][qt] = __builtin_amdgcn_mfma_f32_16x16x32_bf16(av, bp[qt][s], O[ct][qt], 0, 0, 0);
            }
        __builtin_amdgcn_s_setprio(0);
        __syncthreads();   // bar2: PV+ps reads done; V(it+1) DMA drained (vmcnt 0)
    }

    // deferred l reduction (sum over quads per kv-tile)
#pragma unroll
    for (int g = 0; g < 2; ++g) {
        lacc[g] += __shfl_xor(lacc[g], 16);
        lacc[g] += __shfl_xor(lacc[g], 32);
    }
    if (quad == 0) {
#pragma unroll
        for (int g = 0; g < 2; ++g)
            ls[f * TQ + 16 * (2 * qg_ + g) + c16] = lacc[g];
    }
    __syncthreads();

    // store partials: half 0 -> fp32 into outp; half 1 -> bf16 into Op1
    if (half == 0) {
        float* ob = outp + (size_t)(b * C_) * N_;
#pragma unroll
        for (int ct = 0; ct < 4; ++ct)
#pragma unroll
            for (int qt = 0; qt < 2; ++qt) {
                const int n = q0 + 32 * pg + 16 * qt + c16;
#pragma unroll
                for (int r = 0; r < 4; ++r) {
                    const int c = 64 * cs + 16 * ct + 4 * quad + r;
                    ob[(size_t)c * N_ + n] = O[ct][qt][r];
                }
            }
    } else {
        unsigned short* ob = Op1 + (size_t)(b * C_) * N_;
#pragma unroll
        for (int ct = 0; ct < 4; ++ct)
#pragma unroll
            for (int qt = 0; qt < 2; ++qt) {
                const int n = q0 + 32 * pg + 16 * qt + c16;
#pragma unroll
                for (int r = 0; r < 4; ++r) {
                    const int c = 64 * cs + 16 * ct + 4 * quad + r;
                    ob[(size_t)c * N_ + n] = f2bf(O[ct][qt][r]);
                }
            }
    }
    if (w == 0) {
        const int qq = lane;
        const float lv = ls[qq] + ls[TQ + qq] + ls[2 * TQ + qq] + ls[3 * TQ + qq];
        lp[(size_t)(half * B_ + b) * N_ + q0 + qq] = lv;
    }
}

// ---------- combine: out = x + (O0(out) + O1) / (l0 + l1), in place ----------
__global__ __launch_bounds__(256) void combine_kernel(
    const float* __restrict__ x,
    const unsigned short* __restrict__ Op1,
    const float* __restrict__ lp,
    float* __restrict__ out)
{
    __shared__ float linv[1024];

    const int t  = threadIdx.x;
    const int n0 = blockIdx.x * 1024;
    const int c0 = blockIdx.y * 8;
    const int b  = blockIdx.z;

#pragma unroll
    for (int i = 0; i < 4; ++i) {
        const int n = n0 + t + 256 * i;
        const float l = lp[(size_t)b * N_ + n] + lp[(size_t)(B_ + b) * N_ + n];
        linv[t + 256 * i] = 1.0f / l;
    }
    __syncthreads();

#pragma unroll
    for (int cc = 0; cc < 8; ++cc) {
        const int c = c0 + cc;
        const size_t base = ((size_t)(b * C_) + c) * N_ + n0 + 4 * t;
        const f32x4 o0 = *(const f32x4*)&out[base];
        const short4v a1 = *(const short4v*)&Op1[base];
        const f32x4 xv = *(const f32x4*)&x[base];
        f32x4 o;
        o.x = xv.x + (o0.x + bf2f((unsigned short)a1[0])) * linv[4 * t + 0];
        o.y = xv.y + (o0.y + bf2f((unsigned short)a1[1])) * linv[4 * t + 1];
        o.z = xv.z + (o0.z + bf2f((unsigned short)a1[2])) * linv[4 * t + 2];
        o.w = xv.w + (o0.w + bf2f((unsigned short)a1[3])) * linv[4 * t + 3];
        *(f32x4*)&out[base] = o;
    }
}

extern "C" void kernel_launch(void* const* d_in, const int* in_sizes, int n_in,
                              void* d_out, int out_size, void* d_ws, size_t ws_size,
                              hipStream_t stream) {
    const float* x  = (const float*)d_in[0];
    const float* Wq = (const float*)d_in[1];
    const float* bq = (const float*)d_in[2];
    const float* Wk = (const float*)d_in[3];
    const float* bk = (const float*)d_in[4];
    const float* Wv = (const float*)d_in[5];
    const float* bv = (const float*)d_in[6];
    float* out = (float*)d_out;

    unsigned short* ws16 = (unsigned short*)d_ws;
    unsigned short* qb  = ws16;                              // [B][N][32]   1 MB
    unsigned short* kb  = qb + (size_t)B_ * N_ * 32;         // [B][N][32]   1 MB
    unsigned short* vb  = kb + (size_t)B_ * N_ * 32;         // [B][C][N]    8 MB
    unsigned short* Op1 = vb + (size_t)B_ * C_ * N_;         // [B][C][N]    8 MB (bf16 partial, half 1)
    unsigned short* wbf = Op1 + (size_t)B_ * C_ * N_;        // [320][256]   160 KB
    float* biasf = (float*)(wbf + 320 * C_);                 // [320]
    float* lpp   = biasf + 320;                              // [2][B][N]    128 KB

    cvt_w<<<dim3(320), 256, 0, stream>>>(Wq, bq, Wk, bk, Wv, bv, wbf, biasf);
    proj_qkv<<<dim3(N_ / 32, B_), 256, 0, stream>>>(x, wbf, biasf, qb, kb, vb);
    attn_kernel<<<dim3(512), 512, 0, stream>>>(qb, kb, vb, out, Op1, lpp);
    combine_kernel<<<dim3(4, 32, B_), 256, 0, stream>>>(x, Op1, lpp, out);
}

// Round 14
// 144.510 us; speedup vs baseline: 1.0927x; 1.0029x over previous
//
#include <hip/hip_runtime.h>
#include <math.h>

#define B_   4
#define C_   256
#define CQK  32
#define N_   4096
#define TQ   64           // q per attn block (512 blocks -> 2 blocks/CU)
#define TM   64           // kv per chunk
#define HITERS ((N_ / 2) / TM)   // 32 chunks per kv-half
#define PSS  72           // ps row stride (shorts)
#define VSH  (C_ * TM)    // one vs buffer: 16384 shorts (32 KB)
#define XT2  264          // proj xT row stride (shorts): 256 + 8 pad
#define VOS  40           // proj vout row stride (shorts): 32 + 8 pad

typedef __attribute__((ext_vector_type(8))) short short8;
typedef __attribute__((ext_vector_type(4))) short short4v;
typedef __attribute__((ext_vector_type(4))) float f32x4;
typedef __attribute__((ext_vector_type(2))) unsigned int uint2v;

#if __has_builtin(__builtin_amdgcn_exp2f)
#define EXP2F(x) __builtin_amdgcn_exp2f(x)
#else
#define EXP2F(x) exp2f(x)
#endif

// global -> LDS direct DMA, 16B per lane; LDS dest is wave-uniform base + lane*16
typedef const __attribute__((address_space(1))) unsigned int* gas1_t;
typedef __attribute__((address_space(3))) unsigned int* las3_t;
__device__ __forceinline__ void gload_lds16(const unsigned short* g, unsigned short* l) {
    __builtin_amdgcn_global_load_lds((gas1_t)g, (las3_t)l, 16, 0, 0);
}

__device__ __forceinline__ unsigned short f2bf(float f) {
    unsigned u = __builtin_bit_cast(unsigned, f);
    u += 0x7fffu + ((u >> 16) & 1u);
    return (unsigned short)(u >> 16);
}
__device__ __forceinline__ float bf2f(unsigned short s) {
    return __builtin_bit_cast(float, (unsigned)s << 16);
}
__device__ __forceinline__ unsigned pack2bf(float a, float b) {
    unsigned ua = __builtin_bit_cast(unsigned, a) + 0x8000u;
    unsigned ub = __builtin_bit_cast(unsigned, b) + 0x8000u;
#if __has_builtin(__builtin_amdgcn_perm)
    return __builtin_amdgcn_perm(ub, ua, 0x07060302u);
#else
    return (ua >> 16) | (ub & 0xffff0000u);
#endif
}

// ---------- weights -> bf16 [320][256] + fp32 bias[320]; log2e folded into q ----------
__global__ __launch_bounds__(256) void cvt_w(
    const float* __restrict__ Wq, const float* __restrict__ bq,
    const float* __restrict__ Wk, const float* __restrict__ bk,
    const float* __restrict__ Wv, const float* __restrict__ bv,
    unsigned short* __restrict__ wbf, float* __restrict__ biasf)
{
    const float LOG2E = 1.4426950408889634f;
    const int r = blockIdx.x;   // 0..319
    const int t = threadIdx.x;
    const float* src = (r < 32) ? (Wq + r * C_)
                     : (r < 64) ? (Wk + (r - 32) * C_)
                                : (Wv + (r - 64) * C_);
    const float scale = (r < 32) ? LOG2E : 1.0f;
    wbf[r * C_ + t] = f2bf(src[t] * scale);
    if (t == 0)
        biasf[r] = (r < 32) ? bq[r] * LOG2E : (r < 64) ? bk[r - 32] : bv[r - 64];
}

// ---------- fused qkv projection v2: 512 blocks (2/CU), vectorized staging + stores ----------
__global__ __launch_bounds__(256, 2) void proj_qkv(
    const float* __restrict__ x, const unsigned short* __restrict__ wbf,
    const float* __restrict__ biasf,
    unsigned short* __restrict__ qb, unsigned short* __restrict__ kb,
    unsigned short* __restrict__ vb)
{
    __shared__ __align__(16) unsigned short xT[32 * XT2];
    __shared__ __align__(16) unsigned short vout[256 * VOS];
    __shared__ __align__(16) unsigned short qks[32 * 72];

    const int t    = threadIdx.x;
    const int w    = t >> 6;
    const int lane = t & 63;
    const int quad = lane >> 4;
    const int c16  = lane & 15;
    const int n0   = blockIdx.x * 32;
    const int b    = blockIdx.y;

    {
        const int c0 = (t >> 3) * 8;
        const int nq = t & 7;
        f32x4 xv[8];
#pragma unroll
        for (int i = 0; i < 8; ++i)
            xv[i] = *(const f32x4*)&x[((size_t)(b * C_) + c0 + i) * N_ + n0 + 4 * nq];
#pragma unroll
        for (int j = 0; j < 4; ++j) {
            short8 pk;
#pragma unroll
            for (int i = 0; i < 8; ++i) pk[i] = (short)f2bf(xv[i][j]);
            *(short8*)&xT[(4 * nq + j) * XT2 + c0] = pk;
        }
    }
    __syncthreads();

    f32x4 acc[5][2];
#pragma unroll
    for (int i = 0; i < 5; ++i)
#pragma unroll
        for (int nt = 0; nt < 2; ++nt) acc[i][nt] = (f32x4){0.f, 0.f, 0.f, 0.f};

    const unsigned short* wr = wbf + (size_t)(80 * w + c16) * C_ + quad * 8;

#pragma unroll
    for (int ks = 0; ks < 8; ++ks) {
        short8 af[5], bf[2];
#pragma unroll
        for (int i = 0; i < 5; ++i)
            af[i] = *(const short8*)(wr + (size_t)(16 * i) * C_ + 32 * ks);
#pragma unroll
        for (int nt = 0; nt < 2; ++nt)
            bf[nt] = *(const short8*)&xT[(16 * nt + c16) * XT2 + ks * 32 + quad * 8];
#pragma unroll
        for (int i = 0; i < 5; ++i)
#pragma unroll
            for (int nt = 0; nt < 2; ++nt)
                acc[i][nt] = __builtin_amdgcn_mfma_f32_16x16x32_bf16(af[i], bf[nt], acc[i][nt], 0, 0, 0);
    }

#pragma unroll
    for (int i = 0; i < 5; ++i) {
        const int OT = 5 * w + i;
        const int obase = OT * 16 + 4 * quad;
        const f32x4 bv4 = *(const f32x4*)&biasf[obase];
#pragma unroll
        for (int nt = 0; nt < 2; ++nt) {
            const int n = 16 * nt + c16;
            float vals[4];
#pragma unroll
            for (int r = 0; r < 4; ++r) vals[r] = acc[i][nt][r] + bv4[r];
            if (OT >= 4) {
#pragma unroll
                for (int r = 0; r < 4; ++r)
                    vout[(obase + r - 64) * VOS + n] = f2bf(vals[r]);
            } else {
                const int col = (OT < 2 ? 0 : 32) + (OT & 1) * 16 + 4 * quad;
                short4v pk;
#pragma unroll
                for (int r = 0; r < 4; ++r) pk[r] = (short)f2bf(vals[r]);
                *(short4v*)&qks[n * 72 + col] = pk;
            }
        }
    }
    __syncthreads();

#pragma unroll
    for (int p = 0; p < 4; ++p) {
        const int c   = 64 * p + (t >> 2);
        const int seg = t & 3;
        const short8 vv = *(const short8*)&vout[c * VOS + seg * 8];
        *(short8*)(vb + ((size_t)(b * C_) + c) * N_ + n0 + seg * 8) = vv;
    }
    if (w < 2) {
        unsigned short* dst = w ? kb : qb;
        const int coff = w ? 32 : 0;
#pragma unroll
        for (int h = 0; h < 2; ++h) {
            const int n = 16 * h + (lane >> 2);
            const int c = (lane & 3) * 8;
            const short8 v = *(const short8*)&qks[n * 72 + coff + c];
            *(short8*)(dst + ((size_t)(b * N_) + n0 + n) * 32 + c) = v;
        }
    }
}

// ---------- flash attention: R10 structure (proven best); both halves write bf16 partials ----------
// TQ=64, TM=64, split-kv 2-way, 512 blocks (2 blocks/CU, 16 waves/CU).
// V double-buffered via global_load_lds DMA (issued after bar1, drained by bar2's vmcnt);
// K never in LDS (per-wave A-frag from L2, reg-prefetched); 2 barriers/iter.
// grid 512: half = flat&1, b = (flat>>1)&3, q0 = (flat>>3)*64 (XCD-affine in (half,b))
__global__ __launch_bounds__(512, 4) void attn_kernel(
    const unsigned short* __restrict__ qg,
    const unsigned short* __restrict__ kg,
    const unsigned short* __restrict__ vg,
    unsigned short* __restrict__ Op0,  // [B][C][N] bf16 partial (half 0)
    unsigned short* __restrict__ Op1,  // [B][C][N] bf16 partial (half 1)
    float* __restrict__ lp)            // [2][B][N] fp32 l partials
{
    __shared__ __align__(16) unsigned short vs[2 * VSH];    // 64.0 KB 2x [c][kv] swizzled
    __shared__ __align__(16) unsigned short ps[TQ * PSS];   //  9.2 KB [q][kv]
    __shared__ float ls[4 * TQ];                            //  1.0 KB   => 75,776 B total

    const int t    = threadIdx.x;
    const int w    = t >> 6;
    const int lane = t & 63;
    const int quad = lane >> 4;
    const int c16  = lane & 15;
    const int flat = blockIdx.x;
    const int half = flat & 1;
    const int b    = (flat >> 1) & 3;
    const int q0   = (flat >> 3) * TQ;
    const int kvb0 = half * (N_ / 2);
    // S-phase roles
    const int f   = w & 3;      // kv-tile
    const int qg_ = w >> 2;     // q-group: q-tiles 2qg_, 2qg_+1
    // PV roles
    const int cs = w & 3;       // c-stripe (64 c)
    const int pg = w >> 2;      // q-group (32 q)

    const unsigned short* kbase = kg + (size_t)(b * N_) * 32;
    const unsigned short* vbase = vg + (size_t)(b * C_) * N_;

    // hoisted Q B-frags
    short8 bq[2];
#pragma unroll
    for (int g = 0; g < 2; ++g)
        bq[g] = *(const short8*)(qg + ((size_t)(b * N_) + q0 + 16 * (2 * qg_ + g) + c16) * 32 + quad * 8);

    // V DMA mapping: wave w stages rows 32w..32w+31 in 4 instrs of 8 rows (1 KB each).
    // LDS dest linear (base + lane*16); global src pre-swizzled so that
    // vs[c*TM + 8*j] holds V[c][8*(j^(c&7))..+7]
    const int vrow  = lane >> 3;   // 0..7
    const int vslot = lane & 7;    // 16B slot within 128B row

    // K A-frag global offset (per wave f, per lane): 16 rows x 64B, L2-hot
    const size_t koff = (size_t)(16 * f + c16) * 32 + quad * 8;

    // prologue: V(0) via DMA into buf 0; akpre = K(0)
#pragma unroll
    for (int p = 0; p < 4; ++p) {
        const int c = 32 * w + 8 * p + vrow;
        gload_lds16(vbase + (size_t)c * N_ + kvb0 + 8 * (vslot ^ (c & 7)),
                    &vs[(32 * w + 8 * p) * TM]);
    }
    short8 akpre = *(const short8*)(kbase + (size_t)kvb0 * 32 + koff);
    __syncthreads();   // V(0) DMA drained + visible

    f32x4 O[4][2];
#pragma unroll
    for (int ct = 0; ct < 4; ++ct)
#pragma unroll
        for (int qt = 0; qt < 2; ++qt) O[ct][qt] = (f32x4){0.f, 0.f, 0.f, 0.f};

    float lacc[2] = {0.f, 0.f};

#pragma unroll 1
    for (int it = 0; it < HITERS; ++it) {
        const int cur = it & 1;
        const int nxt = cur ^ 1;

        // (1) S^T = K.Q^T for 2 q-tiles (K(it) already in akpre)
        const f32x4 z = {0.f, 0.f, 0.f, 0.f};
        f32x4 sf[2];
#pragma unroll
        for (int g = 0; g < 2; ++g)
            sf[g] = __builtin_amdgcn_mfma_f32_16x16x32_bf16(akpre, bq[g], z, 0, 0, 0);

#pragma unroll
        for (int g = 0; g < 2; ++g) {
            float p[4];
#pragma unroll
            for (int r = 0; r < 4; ++r) p[r] = EXP2F(sf[g][r]);
            lacc[g] += (p[0] + p[1]) + (p[2] + p[3]);
            uint2v u;
            u.x = pack2bf(p[0], p[1]);
            u.y = pack2bf(p[2], p[3]);
            *(uint2v*)&ps[(16 * (2 * qg_ + g) + c16) * PSS + f * 16 + 4 * quad] = u;
        }
        __syncthreads();   // bar1: ps visible; vs[nxt] reads (PV it-1) long done

        // (2) issue V(it+1) DMA into vs[nxt]; prefetch K(it+1) A-frag into regs.
        //     Both complete by bar2's vmcnt drain, hidden under PV.
        if (it + 1 < HITERS) {
            const int kv0n = kvb0 + (it + 1) * TM;
#pragma unroll
            for (int p = 0; p < 4; ++p) {
                const int c = 32 * w + 8 * p + vrow;
                gload_lds16(vbase + (size_t)c * N_ + kv0n + 8 * (vslot ^ (c & 7)),
                            &vs[nxt * VSH + (32 * w + 8 * p) * TM]);
            }
            akpre = *(const short8*)(kbase + (size_t)kv0n * 32 + koff);
        }

        // (3) PV on buffer cur
        short8 bp[2][2];
#pragma unroll
        for (int qt = 0; qt < 2; ++qt)
#pragma unroll
            for (int s = 0; s < 2; ++s)
                bp[qt][s] = *(const short8*)&ps[(32 * pg + 16 * qt + c16) * PSS + 32 * s + 8 * quad];
#pragma unroll
        for (int s = 0; s < 2; ++s)
#pragma unroll
            for (int ct = 0; ct < 4; ++ct) {
                const int c = 64 * cs + 16 * ct + c16;
                const short8 av = *(const short8*)&vs[cur * VSH + c * TM + 8 * ((4 * s + quad) ^ (c & 7))];
#pragma unroll
                for (int qt = 0; qt < 2; ++qt)
                    O[ct][qt] = __builtin_amdgcn_mfma_f32_16x16x32_bf16(av, bp[qt][s], O[ct][qt], 0, 0, 0);
            }
        __syncthreads();   // bar2: PV+ps reads done; V(it+1) DMA drained (vmcnt 0)
    }

    // deferred l reduction (sum over quads per kv-tile)
#pragma unroll
    for (int g = 0; g < 2; ++g) {
        lacc[g] += __shfl_xor(lacc[g], 16);
        lacc[g] += __shfl_xor(lacc[g], 32);
    }
    if (quad == 0) {
#pragma unroll
        for (int g = 0; g < 2; ++g)
            ls[f * TQ + 16 * (2 * qg_ + g) + c16] = lacc[g];
    }
    __syncthreads();

    // store partials: both halves bf16 (halves DRAM traffic vs fp32 half-0)
    unsigned short* ob = (half ? Op1 : Op0) + (size_t)(b * C_) * N_;
#pragma unroll
    for (int ct = 0; ct < 4; ++ct)
#pragma unroll
        for (int qt = 0; qt < 2; ++qt) {
            const int n = q0 + 32 * pg + 16 * qt + c16;
#pragma unroll
            for (int r = 0; r < 4; ++r) {
                const int c = 64 * cs + 16 * ct + 4 * quad + r;
                ob[(size_t)c * N_ + n] = f2bf(O[ct][qt][r]);
            }
        }
    if (w == 0) {
        const int qq = lane;
        const float lv = ls[qq] + ls[TQ + qq] + ls[2 * TQ + qq] + ls[3 * TQ + qq];
        lp[(size_t)(half * B_ + b) * N_ + q0 + qq] = lv;
    }
}

// ---------- combine: out = x + (O0 + O1) / (l0 + l1) ----------
// grid (N/1024 = 4, C/8 = 32, B), 256 threads
__global__ __launch_bounds__(256) void combine_kernel(
    const float* __restrict__ x,
    const unsigned short* __restrict__ Op0,
    const unsigned short* __restrict__ Op1,
    const float* __restrict__ lp,
    float* __restrict__ out)
{
    __shared__ float linv[1024];

    const int t  = threadIdx.x;
    const int n0 = blockIdx.x * 1024;
    const int c0 = blockIdx.y * 8;
    const int b  = blockIdx.z;

#pragma unroll
    for (int i = 0; i < 4; ++i) {
        const int n = n0 + t + 256 * i;
        const float l = lp[(size_t)b * N_ + n] + lp[(size_t)(B_ + b) * N_ + n];
        linv[t + 256 * i] = 1.0f / l;
    }
    __syncthreads();

#pragma unroll
    for (int cc = 0; cc < 8; ++cc) {
        const int c = c0 + cc;
        const size_t base = ((size_t)(b * C_) + c) * N_ + n0 + 4 * t;
        const short4v a0 = *(const short4v*)&Op0[base];
        const short4v a1 = *(const short4v*)&Op1[base];
        const f32x4 xv = *(const f32x4*)&x[base];
        f32x4 o;
#pragma unroll
        for (int r = 0; r < 4; ++r) {
            const float s = bf2f((unsigned short)a0[r]) + bf2f((unsigned short)a1[r]);
            o[r] = xv[r] + s * linv[4 * t + r];
        }
        *(f32x4*)&out[base] = o;
    }
}

extern "C" void kernel_launch(void* const* d_in, const int* in_sizes, int n_in,
                              void* d_out, int out_size, void* d_ws, size_t ws_size,
                              hipStream_t stream) {
    const float* x  = (const float*)d_in[0];
    const float* Wq = (const float*)d_in[1];
    const float* bq = (const float*)d_in[2];
    const float* Wk = (const float*)d_in[3];
    const float* bk = (const float*)d_in[4];
    const float* Wv = (const float*)d_in[5];
    const float* bv = (const float*)d_in[6];
    float* out = (float*)d_out;

    unsigned short* ws16 = (unsigned short*)d_ws;
    unsigned short* qb  = ws16;                              // [B][N][32]   1 MB
    unsigned short* kb  = qb + (size_t)B_ * N_ * 32;         // [B][N][32]   1 MB
    unsigned short* vb  = kb + (size_t)B_ * N_ * 32;         // [B][C][N]    8 MB
    unsigned short* Op0 = vb + (size_t)B_ * C_ * N_;         // [B][C][N]    8 MB (bf16 partial, half 0)
    unsigned short* Op1 = Op0 + (size_t)B_ * C_ * N_;        // [B][C][N]    8 MB (bf16 partial, half 1)
    unsigned short* wbf = Op1 + (size_t)B_ * C_ * N_;        // [320][256]   160 KB
    float* biasf = (float*)(wbf + 320 * C_);                 // [320]
    float* lpp   = biasf + 320;                              // [2][B][N]    128 KB

    cvt_w<<<dim3(320), 256, 0, stream>>>(Wq, bq, Wk, bk, Wv, bv, wbf, biasf);
    proj_qkv<<<dim3(N_ / 32, B_), 256, 0, stream>>>(x, wbf, biasf, qb, kb, vb);
    attn_kernel<<<dim3(512), 512, 0, stream>>>(qb, kb, vb, Op0, Op1, lpp);
    combine_kernel<<<dim3(4, 32, B_), 256, 0, stream>>>(x, Op0, Op1, lpp, out);
}